// Round 2
// baseline (328.523 us; speedup 1.0000x reference)
//
#include <hip/hip_runtime.h>
#include <math.h>

#define NQ 10
#define NL 4
#define NA (NQ * NL)
#define PI_F 3.14159265358979323846f

__device__ __forceinline__ float wave_sum(float v) {
#pragma unroll
  for (int m = 1; m < 64; m <<= 1) v += __shfl_xor(v, m, 64);
  return v;
}

// One wave (64 lanes) per batch element. State index i = lane*16 + r.
// Wire q lives at bit (9-q) of i: wires 0..5 -> lane bits 5..0,
// wires 6..9 -> register bits 3..0.
__global__ __launch_bounds__(256, 3) void qsim_kernel(
    const float* __restrict__ x, const float* __restrict__ w,
    float* __restrict__ out, int batch) {
  const int lane = threadIdx.x & 63;
  const int wid = blockIdx.x * (blockDim.x >> 6) + (threadIdx.x >> 6);
  if (wid >= batch) return;

  // ---- per-lane precompute: lane j < 40 owns gate j = l*10 + q ----
  float ca = 1.f, sa = 0.f, Pr = 0.f, Pi = 0.f, Qr = 0.f, Qi = 0.f;
  if (lane < NA) {
    float xv = x[wid * NA + lane];
    float a = 0.5f * PI_F * atanf(xv);   // half of data-reuploading angle
    sincosf(a, &sa, &ca);
    float w0 = w[2 * lane], w1 = w[2 * lane + 1];
    float sphi, cphi, sw, cw;
    sincosf(0.5f * w0, &sphi, &cphi);
    sincosf(0.5f * w1, &sw, &cw);
    Pr = cw * cphi; Pi = -cw * sphi;   // P = cos(w1/2) * e^{-i w0/2}
    Qr = sw * cphi; Qi = sw * sphi;    // Q = sin(w1/2) * e^{+i w0/2}
  }

  // ---- state registers ----
  float sr[16], si[16];
#pragma unroll
  for (int r = 0; r < 16; ++r) { sr[r] = 0.f; si[r] = 0.f; }
  if (lane == 0) sr[0] = 1.f;  // |0...0>

  // composed CNOT(q,q+1), q=0..4 on lane bits: gather src = gray(lane)
  const int permSrc = lane ^ (lane >> 1);

#pragma unroll 1
  for (int l = 0; l < NL; ++l) {
    // ---------- 10 single-qubit gates U = RY(w1) RZ(w0) RY(a) ----------
#pragma unroll
    for (int q = 0; q < NQ; ++q) {
      const int j = l * NQ + q;
      const float cA = __shfl(ca, j), sA = __shfl(sa, j);
      const float pr = __shfl(Pr, j), pi = __shfl(Pi, j);
      const float qr = __shfl(Qr, j), qi = __shfl(Qi, j);
      // u00 = cA*P - sA*Q ; u01 = -(sA*P + cA*Q); u10=-conj(u01); u11=conj(u00)
      const float u00r = cA * pr - sA * qr;
      const float u00i = cA * pi - sA * qi;
      const float u01r = -(sA * pr + cA * qr);
      const float u01i = -(sA * pi + cA * qi);
      if (q >= 6) {
        // register-local pairs, bit B = 9-q
        const int B = 9 - q;
#pragma unroll
        for (int rlo = 0; rlo < 16; ++rlo) {
          if (rlo & (1 << B)) continue;
          const int rhi = rlo | (1 << B);
          float lr = sr[rlo], li = si[rlo];
          float hr = sr[rhi], hi = si[rhi];
          sr[rlo] = u00r * lr - u00i * li + u01r * hr - u01i * hi;
          si[rlo] = u00r * li + u00i * lr + u01r * hi + u01i * hr;
          sr[rhi] = -u01r * lr - u01i * li + u00r * hr + u00i * hi;
          si[rhi] = -u01r * li + u01i * lr + u00r * hi - u00i * hr;
        }
      } else {
        // cross-lane pairs, lane bit Lb = 5-q
        const int Lb = 5 - q;
        const int m = 1 << Lb;
        const bool bit = ((lane >> Lb) & 1) != 0;
        // new = A*mine + B*partner; A = bit?u11:u00, B = bit?u10:u01
        const float Ar = u00r;                    // u11r == u00r
        const float Ai = bit ? -u00i : u00i;
        const float Br = bit ? -u01r : u01r;
        const float Bi = u01i;                    // u10i == u01i
#pragma unroll
        for (int r = 0; r < 16; ++r) {
          float prr = __shfl_xor(sr[r], m);
          float pri = __shfl_xor(si[r], m);
          float mr = sr[r], mi = si[r];
          sr[r] = Ar * mr - Ai * mi + Br * prr - Bi * pri;
          si[r] = Ar * mi + Ai * mr + Br * pri + Bi * prr;
        }
      }
    }

    // ---------- CNOT ring, q: q -> q+1 mod 10, applied in order ----------
    // q=0..4 composed: pure lane permutation (gather from gray(lane))
#pragma unroll
    for (int r = 0; r < 16; ++r) {
      sr[r] = __shfl(sr[r], permSrc);
      si[r] = __shfl(si[r], permSrc);
    }
    // q=5: control wire5 = lane bit0, target wire6 = reg bit3 -> cond swap r<->r^8
    {
      const bool c5 = (lane & 1) != 0;
#pragma unroll
      for (int r = 0; r < 8; ++r) {
        float ar = sr[r], ai = si[r], br = sr[r + 8], bi = si[r + 8];
        sr[r] = c5 ? br : ar;      si[r] = c5 ? bi : ai;
        sr[r + 8] = c5 ? ar : br;  si[r + 8] = c5 ? ai : bi;
      }
    }
    // q=6..8 composed: register gather new[j] = old[gray(j)]
    // cycles: (2 3) (4 6 5 7) (8 12 10 15) (9 13 11 14)
    {
      float t;
      t = sr[2]; sr[2] = sr[3]; sr[3] = t;
      t = si[2]; si[2] = si[3]; si[3] = t;
      t = sr[4]; sr[4] = sr[6]; sr[6] = sr[5]; sr[5] = sr[7]; sr[7] = t;
      t = si[4]; si[4] = si[6]; si[6] = si[5]; si[5] = si[7]; si[7] = t;
      t = sr[8]; sr[8] = sr[12]; sr[12] = sr[10]; sr[10] = sr[15]; sr[15] = t;
      t = si[8]; si[8] = si[12]; si[12] = si[10]; si[10] = si[15]; si[15] = t;
      t = sr[9]; sr[9] = sr[13]; sr[13] = sr[11]; sr[11] = sr[14]; sr[14] = t;
      t = si[9]; si[9] = si[13]; si[13] = si[11]; si[11] = si[14]; si[14] = t;
    }
    // q=9: control wire9 = reg bit0, target wire0 = lane bit5 -> odd r swap lane^32
#pragma unroll
    for (int r = 1; r < 16; r += 2) {
      sr[r] = __shfl_xor(sr[r], 32);
      si[r] = __shfl_xor(si[r], 32);
    }
  }

  // ---------- epilogue: <Z_q> = sum_{bit q=0} p - sum_{bit q=1} p ----------
  float tot = 0.f, t0 = 0.f, t1 = 0.f, t2 = 0.f, t3 = 0.f;
#pragma unroll
  for (int r = 0; r < 16; ++r) {
    float pv = sr[r] * sr[r] + si[r] * si[r];
    tot += pv;
    if (r & 1) t0 += pv;
    if (r & 2) t1 += pv;
    if (r & 4) t2 += pv;
    if (r & 8) t3 += pv;
  }
  float z[NQ];
  z[6] = tot - 2.f * t3;  // wire6 = reg bit3
  z[7] = tot - 2.f * t2;
  z[8] = tot - 2.f * t1;
  z[9] = tot - 2.f * t0;
  z[0] = (lane & 32) ? -tot : tot;  // wire0 = lane bit5
  z[1] = (lane & 16) ? -tot : tot;
  z[2] = (lane & 8) ? -tot : tot;
  z[3] = (lane & 4) ? -tot : tot;
  z[4] = (lane & 2) ? -tot : tot;
  z[5] = (lane & 1) ? -tot : tot;
#pragma unroll
  for (int q = 0; q < NQ; ++q) z[q] = wave_sum(z[q]);
  if (lane == 0) {
#pragma unroll
    for (int q = 0; q < NQ; ++q) out[wid * NQ + q] = z[q];
  }
}

extern "C" void kernel_launch(void* const* d_in, const int* in_sizes, int n_in,
                              void* d_out, int out_size, void* d_ws, size_t ws_size,
                              hipStream_t stream) {
  const float* x = (const float*)d_in[0];
  const float* w = (const float*)d_in[1];
  float* out = (float*)d_out;
  const int batch = in_sizes[0] / NA;
  const int wavesPerBlock = 4;  // 256 threads
  const int blocks = (batch + wavesPerBlock - 1) / wavesPerBlock;
  qsim_kernel<<<blocks, 256, 0, stream>>>(x, w, out, batch);
}

// Round 3
// 299.502 us; speedup vs baseline: 1.0969x; 1.0969x over previous
//
#include <hip/hip_runtime.h>
#include <math.h>

#define NQ 10
#define NL 4
#define NA (NQ * NL)
#define PI_F 3.14159265358979323846f

// ---- cross-lane xor shuffle, routed to cheapest pipe per mask ----
// DPP quad_perm handles xor1/xor2 (VALU pipe). ROW_MIRROR/HALF_MIRROR are
// xor15/xor7, NOT xor8/xor4 -> masks 4,8,16 use ds_swizzle (DS pipe),
// mask 32 crosses 32-lane halves -> __shfl_xor (ds_permute).
template <int MASK>
__device__ __forceinline__ float shfl_xor_f(float v) {
  if constexpr (MASK == 1) {
    int r = __builtin_amdgcn_update_dpp(__float_as_int(v), __float_as_int(v),
                                        0xB1 /*quad_perm(1,0,3,2)*/, 0xF, 0xF, true);
    return __int_as_float(r);
  } else if constexpr (MASK == 2) {
    int r = __builtin_amdgcn_update_dpp(__float_as_int(v), __float_as_int(v),
                                        0x4E /*quad_perm(2,3,0,1)*/, 0xF, 0xF, true);
    return __int_as_float(r);
  } else if constexpr (MASK == 4) {
    return __int_as_float(__builtin_amdgcn_ds_swizzle(__float_as_int(v), 0x101F));
  } else if constexpr (MASK == 8) {
    return __int_as_float(__builtin_amdgcn_ds_swizzle(__float_as_int(v), 0x201F));
  } else if constexpr (MASK == 16) {
    return __int_as_float(__builtin_amdgcn_ds_swizzle(__float_as_int(v), 0x401F));
  } else {
    return __shfl_xor(v, MASK, 64);
  }
}

// uniform-index broadcast without the DS pipe (v_readlane_b32)
__device__ __forceinline__ float readlane_f(float v, int l) {
  return __int_as_float(__builtin_amdgcn_readlane(__float_as_int(v), l));
}

__device__ __forceinline__ float wave_sum_h(float v) {
  v += shfl_xor_f<1>(v);
  v += shfl_xor_f<2>(v);
  v += shfl_xor_f<4>(v);
  v += shfl_xor_f<8>(v);
  v += shfl_xor_f<16>(v);
  v += shfl_xor_f<32>(v);
  return v;
}

// SU(2) gate coefficients for gate j, broadcast from owning lane via readlane.
__device__ __forceinline__ void gate_coefs(int j, float ca, float sa, float Pr,
                                           float Pi, float Qr, float Qi,
                                           float& u00r, float& u00i,
                                           float& u01r, float& u01i) {
  const float cA = readlane_f(ca, j), sA = readlane_f(sa, j);
  const float pr = readlane_f(Pr, j), pi = readlane_f(Pi, j);
  const float qr = readlane_f(Qr, j), qi = readlane_f(Qi, j);
  u00r = cA * pr - sA * qr;
  u00i = cA * pi - sA * qi;
  u01r = -(sA * pr + cA * qr);
  u01i = -(sA * pi + cA * qi);
}

// gate on a lane-bit wire: pairs lane <-> lane ^ (1<<LB)
template <int LB>
__device__ __forceinline__ void cross_gate(float (&sr)[16], float (&si)[16],
                                           float u00r, float u00i, float u01r,
                                           float u01i, int lane) {
  const bool bit = (lane & (1 << LB)) != 0;
  // new = A*mine + B*partner; A = bit?u11:u00, B = bit?u10:u01
  const float Ar = u00r;                    // u11r == u00r
  const float Ai = bit ? -u00i : u00i;
  const float Br = bit ? -u01r : u01r;
  const float Bi = u01i;                    // u10i == u01i
#pragma unroll
  for (int r = 0; r < 16; ++r) {
    float prr = shfl_xor_f<(1 << LB)>(sr[r]);
    float pri = shfl_xor_f<(1 << LB)>(si[r]);
    float mr = sr[r], mi = si[r];
    sr[r] = Ar * mr - Ai * mi + Br * prr - Bi * pri;
    si[r] = Ar * mi + Ai * mr + Br * pri + Bi * prr;
  }
}

// gate on a register-bit wire: pairs r <-> r | (1<<B), register-local
template <int B>
__device__ __forceinline__ void local_gate(float (&sr)[16], float (&si)[16],
                                           float u00r, float u00i, float u01r,
                                           float u01i) {
#pragma unroll
  for (int rlo = 0; rlo < 16; ++rlo) {
    if (rlo & (1 << B)) continue;
    const int rhi = rlo | (1 << B);
    float lr = sr[rlo], li = si[rlo];
    float hr = sr[rhi], hi = si[rhi];
    sr[rlo] = u00r * lr - u00i * li + u01r * hr - u01i * hi;
    si[rlo] = u00r * li + u00i * lr + u01r * hi + u01i * hr;
    sr[rhi] = -u01r * lr - u01i * li + u00r * hr + u00i * hi;
    si[rhi] = -u01r * li + u01i * lr + u00r * hi - u00i * hr;
  }
}

// One wave (64 lanes) per batch element. State index i = lane*16 + r.
// Wire q at bit (9-q): wires 0..5 -> lane bits 5..0, wires 6..9 -> reg bits 3..0.
__global__ __launch_bounds__(256, 3) void qsim_kernel(
    const float* __restrict__ x, const float* __restrict__ w,
    float* __restrict__ out, int batch) {
  const int lane = threadIdx.x & 63;
  const int wid = blockIdx.x * (blockDim.x >> 6) + (threadIdx.x >> 6);
  if (wid >= batch) return;

  // ---- per-lane precompute: lane j < 40 owns gate j = l*10 + q ----
  float ca = 1.f, sa = 0.f, Pr = 0.f, Pi = 0.f, Qr = 0.f, Qi = 0.f;
  if (lane < NA) {
    float xv = x[wid * NA + lane];
    float a = 0.5f * PI_F * atanf(xv);  // half of data-reuploading angle
    sincosf(a, &sa, &ca);
    float w0 = w[2 * lane], w1 = w[2 * lane + 1];
    float sphi, cphi, sw, cw;
    sincosf(0.5f * w0, &sphi, &cphi);
    sincosf(0.5f * w1, &sw, &cw);
    Pr = cw * cphi; Pi = -cw * sphi;  // P = cos(w1/2) * e^{-i w0/2}
    Qr = sw * cphi; Qi = sw * sphi;   // Q = sin(w1/2) * e^{+i w0/2}
  }

  float sr[16], si[16];
#pragma unroll
  for (int r = 0; r < 16; ++r) { sr[r] = 0.f; si[r] = 0.f; }
  if (lane == 0) sr[0] = 1.f;  // |0...0>

  // composed CNOT(q,q+1), q=0..4 on lane bits: gather src = gray(lane)
  const int permSrc = lane ^ (lane >> 1);

#pragma unroll 1
  for (int l = 0; l < NL; ++l) {
    const int j0 = l * NQ;
    float u00r, u00i, u01r, u01i;
    // ---------- 10 single-qubit gates U = RY(w1) RZ(w0) RY(a) ----------
    gate_coefs(j0 + 0, ca, sa, Pr, Pi, Qr, Qi, u00r, u00i, u01r, u01i);
    cross_gate<5>(sr, si, u00r, u00i, u01r, u01i, lane);
    gate_coefs(j0 + 1, ca, sa, Pr, Pi, Qr, Qi, u00r, u00i, u01r, u01i);
    cross_gate<4>(sr, si, u00r, u00i, u01r, u01i, lane);
    gate_coefs(j0 + 2, ca, sa, Pr, Pi, Qr, Qi, u00r, u00i, u01r, u01i);
    cross_gate<3>(sr, si, u00r, u00i, u01r, u01i, lane);
    gate_coefs(j0 + 3, ca, sa, Pr, Pi, Qr, Qi, u00r, u00i, u01r, u01i);
    cross_gate<2>(sr, si, u00r, u00i, u01r, u01i, lane);
    gate_coefs(j0 + 4, ca, sa, Pr, Pi, Qr, Qi, u00r, u00i, u01r, u01i);
    cross_gate<1>(sr, si, u00r, u00i, u01r, u01i, lane);
    gate_coefs(j0 + 5, ca, sa, Pr, Pi, Qr, Qi, u00r, u00i, u01r, u01i);
    cross_gate<0>(sr, si, u00r, u00i, u01r, u01i, lane);
    gate_coefs(j0 + 6, ca, sa, Pr, Pi, Qr, Qi, u00r, u00i, u01r, u01i);
    local_gate<3>(sr, si, u00r, u00i, u01r, u01i);
    gate_coefs(j0 + 7, ca, sa, Pr, Pi, Qr, Qi, u00r, u00i, u01r, u01i);
    local_gate<2>(sr, si, u00r, u00i, u01r, u01i);
    gate_coefs(j0 + 8, ca, sa, Pr, Pi, Qr, Qi, u00r, u00i, u01r, u01i);
    local_gate<1>(sr, si, u00r, u00i, u01r, u01i);
    gate_coefs(j0 + 9, ca, sa, Pr, Pi, Qr, Qi, u00r, u00i, u01r, u01i);
    local_gate<0>(sr, si, u00r, u00i, u01r, u01i);

    // ---------- CNOT ring, q -> q+1 mod 10 ----------
    // q=0..4 composed: pure lane permutation (gather from gray(lane))
#pragma unroll
    for (int r = 0; r < 16; ++r) {
      sr[r] = __shfl(sr[r], permSrc);
      si[r] = __shfl(si[r], permSrc);
    }
    // q=5: control wire5 = lane bit0, target wire6 = reg bit3 -> cond swap r<->r^8
    {
      const bool c5 = (lane & 1) != 0;
#pragma unroll
      for (int r = 0; r < 8; ++r) {
        float ar = sr[r], ai = si[r], br = sr[r + 8], bi = si[r + 8];
        sr[r] = c5 ? br : ar;      si[r] = c5 ? bi : ai;
        sr[r + 8] = c5 ? ar : br;  si[r + 8] = c5 ? ai : bi;
      }
    }
    // q=6..8 composed: register gather new[j] = old[gray(j)]
    // cycles: (2 3) (4 6 5 7) (8 12 10 15) (9 13 11 14)
    {
      float t;
      t = sr[2]; sr[2] = sr[3]; sr[3] = t;
      t = si[2]; si[2] = si[3]; si[3] = t;
      t = sr[4]; sr[4] = sr[6]; sr[6] = sr[5]; sr[5] = sr[7]; sr[7] = t;
      t = si[4]; si[4] = si[6]; si[6] = si[5]; si[5] = si[7]; si[7] = t;
      t = sr[8]; sr[8] = sr[12]; sr[12] = sr[10]; sr[10] = sr[15]; sr[15] = t;
      t = si[8]; si[8] = si[12]; si[12] = si[10]; si[10] = si[15]; si[15] = t;
      t = sr[9]; sr[9] = sr[13]; sr[13] = sr[11]; sr[11] = sr[14]; sr[14] = t;
      t = si[9]; si[9] = si[13]; si[13] = si[11]; si[11] = si[14]; si[14] = t;
    }
    // q=9: control wire9 = reg bit0, target wire0 = lane bit5 -> odd r swap lane^32
#pragma unroll
    for (int r = 1; r < 16; r += 2) {
      sr[r] = __shfl_xor(sr[r], 32);
      si[r] = __shfl_xor(si[r], 32);
    }
  }

  // ---------- epilogue ----------
  float tot = 0.f, t0 = 0.f, t1 = 0.f, t2 = 0.f, t3 = 0.f;
#pragma unroll
  for (int r = 0; r < 16; ++r) {
    float pv = sr[r] * sr[r] + si[r] * si[r];
    tot += pv;
    if (r & 1) t0 += pv;
    if (r & 2) t1 += pv;
    if (r & 4) t2 += pv;
    if (r & 8) t3 += pv;
  }
  // full sums of register-bit partials (result in all lanes)
  const float S3 = wave_sum_h(t3);
  const float S2 = wave_sum_h(t2);
  const float S1 = wave_sum_h(t1);
  const float S0 = wave_sum_h(t0);
  // Walsh-Hadamard transform of tot across lanes: after 6 butterfly stages,
  // lane L holds sum_i (-1)^popcnt(L&i) tot_i. Single-bit L gives the six
  // lane-wire <Z> values; lane 0 holds sum(tot).
  float v = tot, h;
  h = shfl_xor_f<1>(v);  v = (lane & 1)  ? h - v : v + h;
  h = shfl_xor_f<2>(v);  v = (lane & 2)  ? h - v : v + h;
  h = shfl_xor_f<4>(v);  v = (lane & 4)  ? h - v : v + h;
  h = shfl_xor_f<8>(v);  v = (lane & 8)  ? h - v : v + h;
  h = shfl_xor_f<16>(v); v = (lane & 16) ? h - v : v + h;
  h = shfl_xor_f<32>(v); v = (lane & 32) ? h - v : v + h;

  float* o = out + wid * NQ;
  if (lane == 32) o[0] = v;  // wire0 sign = lane bit5
  if (lane == 16) o[1] = v;
  if (lane == 8)  o[2] = v;
  if (lane == 4)  o[3] = v;
  if (lane == 2)  o[4] = v;
  if (lane == 1)  o[5] = v;  // wire5 sign = lane bit0
  if (lane == 0) {
    o[6] = v - 2.f * S3;  // wire6 = reg bit3; v(lane0) = sum(tot)
    o[7] = v - 2.f * S2;
    o[8] = v - 2.f * S1;
    o[9] = v - 2.f * S0;
  }
}

extern "C" void kernel_launch(void* const* d_in, const int* in_sizes, int n_in,
                              void* d_out, int out_size, void* d_ws, size_t ws_size,
                              hipStream_t stream) {
  const float* x = (const float*)d_in[0];
  const float* w = (const float*)d_in[1];
  float* out = (float*)d_out;
  const int batch = in_sizes[0] / NA;
  const int wavesPerBlock = 4;  // 256 threads
  const int blocks = (batch + wavesPerBlock - 1) / wavesPerBlock;
  qsim_kernel<<<blocks, 256, 0, stream>>>(x, w, out, batch);
}

// Round 4
// 179.836 us; speedup vs baseline: 1.8268x; 1.6654x over previous
//
#include <hip/hip_runtime.h>
#include <math.h>

#define NQ 10
#define NL 4
#define NA (NQ * NL)
#define PI_F 3.14159265358979323846f

typedef float f32x2 __attribute__((ext_vector_type(2)));

// ---------------- packed complex arithmetic (VOP3P) ----------------
// State amp s = (re, im) in a VGPR pair. Coefficient c applied with sign
// pattern <SR, SI>: c_eff = (SR*c.re, SI*c.im). Complex product:
//   d.lo = SR*cr*sr - SI*ci*si ; d.hi = SR*cr*si + SI*ci*sr
// Two VOP3P instrs; swaps/negations fold into op_sel / neg modifiers.
template <int SR, int SI>
__device__ __forceinline__ f32x2 cmul_sg(f32x2 c, f32x2 s) {
  f32x2 d;
  if constexpr (SR > 0) {
    asm("v_pk_mul_f32 %0, %1, %2 op_sel_hi:[0,1]"
        : "=v"(d) : "v"(c), "v"(s));
  } else {
    asm("v_pk_mul_f32 %0, %1, %2 op_sel_hi:[0,1] neg_lo:[1,0] neg_hi:[1,0]"
        : "=v"(d) : "v"(c), "v"(s));
  }
  if constexpr (SI > 0) {
    asm("v_pk_fma_f32 %0, %1, %2, %0 op_sel:[1,1,0] op_sel_hi:[1,0,1] neg_lo:[1,0,0]"
        : "+v"(d) : "v"(c), "v"(s));
  } else {
    asm("v_pk_fma_f32 %0, %1, %2, %0 op_sel:[1,1,0] op_sel_hi:[1,0,1] neg_hi:[1,0,0]"
        : "+v"(d) : "v"(c), "v"(s));
  }
  return d;
}

template <int SR, int SI>
__device__ __forceinline__ f32x2 cfma_sg(f32x2 c, f32x2 s, f32x2 acc) {
  f32x2 d;
  if constexpr (SR > 0) {
    asm("v_pk_fma_f32 %0, %1, %2, %3 op_sel_hi:[0,1,1]"
        : "=v"(d) : "v"(c), "v"(s), "v"(acc));
  } else {
    asm("v_pk_fma_f32 %0, %1, %2, %3 op_sel_hi:[0,1,1] neg_lo:[1,0,0] neg_hi:[1,0,0]"
        : "=v"(d) : "v"(c), "v"(s), "v"(acc));
  }
  if constexpr (SI > 0) {
    asm("v_pk_fma_f32 %0, %1, %2, %0 op_sel:[1,1,0] op_sel_hi:[1,0,1] neg_lo:[1,0,0]"
        : "+v"(d) : "v"(c), "v"(s));
  } else {
    asm("v_pk_fma_f32 %0, %1, %2, %0 op_sel:[1,1,0] op_sel_hi:[1,0,1] neg_hi:[1,0,0]"
        : "+v"(d) : "v"(c), "v"(s));
  }
  return d;
}

// ---- cross-lane xor shuffle, routed per mask: DPP (VALU) for 1,2;
// ds_swizzle for 4,8,16; ds_permute (__shfl_xor) for 32. ----
template <int MASK>
__device__ __forceinline__ float shfl_xor_f(float v) {
  if constexpr (MASK == 1) {
    int r = __builtin_amdgcn_update_dpp(__float_as_int(v), __float_as_int(v),
                                        0xB1 /*quad_perm(1,0,3,2)*/, 0xF, 0xF, true);
    return __int_as_float(r);
  } else if constexpr (MASK == 2) {
    int r = __builtin_amdgcn_update_dpp(__float_as_int(v), __float_as_int(v),
                                        0x4E /*quad_perm(2,3,0,1)*/, 0xF, 0xF, true);
    return __int_as_float(r);
  } else if constexpr (MASK == 4) {
    return __int_as_float(__builtin_amdgcn_ds_swizzle(__float_as_int(v), 0x101F));
  } else if constexpr (MASK == 8) {
    return __int_as_float(__builtin_amdgcn_ds_swizzle(__float_as_int(v), 0x201F));
  } else if constexpr (MASK == 16) {
    return __int_as_float(__builtin_amdgcn_ds_swizzle(__float_as_int(v), 0x401F));
  } else {
    return __shfl_xor(v, MASK, 64);
  }
}

__device__ __forceinline__ float readlane_f(float v, int l) {
  return __int_as_float(__builtin_amdgcn_readlane(__float_as_int(v), l));
}

__device__ __forceinline__ float wave_sum_h(float v) {
  v += shfl_xor_f<1>(v);
  v += shfl_xor_f<2>(v);
  v += shfl_xor_f<4>(v);
  v += shfl_xor_f<8>(v);
  v += shfl_xor_f<16>(v);
  v += shfl_xor_f<32>(v);
  return v;
}

// gate on a lane-bit wire: pairs lane <-> lane ^ (1<<LB); new = A*mine + B*partner
template <int LB>
__device__ __forceinline__ void cross_gate(f32x2 (&sv)[16], f32x2 A, f32x2 B) {
#pragma unroll
  for (int r = 0; r < 16; ++r) {
    f32x2 p;
    p.x = shfl_xor_f<(1 << LB)>(sv[r].x);
    p.y = shfl_xor_f<(1 << LB)>(sv[r].y);
    sv[r] = cfma_sg<1, 1>(B, p, cmul_sg<1, 1>(A, sv[r]));
  }
}

// gate on a register-bit wire: pairs r <-> r | (1<<RB), register-local.
// lo' = u00*lo + u01*hi ; hi' = -conj(u01)*lo + conj(u00)*hi
template <int RB>
__device__ __forceinline__ void local_gate(f32x2 (&sv)[16], f32x2 u00, f32x2 u01) {
#pragma unroll
  for (int rlo = 0; rlo < 16; ++rlo) {
    if (rlo & (1 << RB)) continue;
    const int rhi = rlo | (1 << RB);
    f32x2 lo = sv[rlo], hi = sv[rhi];
    sv[rlo] = cfma_sg<1, 1>(u01, hi, cmul_sg<1, 1>(u00, lo));
    sv[rhi] = cfma_sg<1, -1>(u00, hi, cmul_sg<-1, 1>(u01, lo));
  }
}

// One wave (64 lanes) per batch element. State index i = lane*16 + r.
// Wire q at bit (9-q): wires 0..5 -> lane bits 5..0, wires 6..9 -> reg bits 3..0.
__global__ __launch_bounds__(256, 4) void qsim_kernel(
    const float* __restrict__ x, const float* __restrict__ w,
    float* __restrict__ out, int batch) {
  const int lane = threadIdx.x & 63;
  const int wid = blockIdx.x * (blockDim.x >> 6) + (threadIdx.x >> 6);
  if (wid >= batch) return;

  // ---- prologue: lane j < 40 owns gate j = l*10 + q; full SU(2) coefs ----
  float U00r = 0.f, U00i = 0.f, U01r = 0.f, U01i = 0.f;
  if (lane < NA) {
    float xv = x[wid * NA + lane];
    float a = 0.5f * PI_F * atanf(xv);  // half of data-reuploading angle
    float sa, ca;
    sincosf(a, &sa, &ca);
    float w0 = w[2 * lane], w1 = w[2 * lane + 1];
    float sphi, cphi, sw, cw;
    sincosf(0.5f * w0, &sphi, &cphi);
    sincosf(0.5f * w1, &sw, &cw);
    const float Pr = cw * cphi, Pi = -cw * sphi;  // P = cos(w1/2) e^{-i w0/2}
    const float Qr = sw * cphi, Qi = sw * sphi;   // Q = sin(w1/2) e^{+i w0/2}
    U00r = ca * Pr - sa * Qr;
    U00i = ca * Pi - sa * Qi;
    U01r = -(sa * Pr + ca * Qr);
    U01i = -(sa * Pi + ca * Qi);
  }

  f32x2 sv[16];
#pragma unroll
  for (int r = 0; r < 16; ++r) sv[r] = f32x2{0.f, 0.f};
  if (lane == 0) sv[0].x = 1.f;  // |0...0>

  // composed CNOT(q,q+1), q=0..4 on lane bits: gather src = gray(lane)
  const int permSrc = lane ^ (lane >> 1);

#pragma unroll 1
  for (int l = 0; l < NL; ++l) {
    const int j0 = l * NQ;
    // ---------- 10 single-qubit gates U = RY(w1) RZ(w0) RY(a) ----------
#define GET_U(j)                                                   \
  const f32x2 u00 = {readlane_f(U00r, (j)), readlane_f(U00i, (j))}; \
  const f32x2 u01 = {readlane_f(U01r, (j)), readlane_f(U01i, (j))}
#define CROSS(q, LB)                                               \
  {                                                                \
    GET_U(j0 + (q));                                               \
    const bool bit = (lane & (1 << (LB))) != 0;                    \
    const f32x2 A = {u00.x, bit ? -u00.y : u00.y};                 \
    const f32x2 B = {bit ? -u01.x : u01.x, u01.y};                 \
    cross_gate<(LB)>(sv, A, B);                                    \
  }
#define LOCAL(q, RB)                                               \
  {                                                                \
    GET_U(j0 + (q));                                               \
    local_gate<(RB)>(sv, u00, u01);                                \
  }
    CROSS(0, 5)
    CROSS(1, 4)
    CROSS(2, 3)
    CROSS(3, 2)
    CROSS(4, 1)
    CROSS(5, 0)
    LOCAL(6, 3)
    LOCAL(7, 2)
    LOCAL(8, 1)
    LOCAL(9, 0)
#undef GET_U
#undef CROSS
#undef LOCAL

    // ---------- CNOT ring, q -> q+1 mod 10 ----------
    // q=0..4 composed: pure lane permutation (gather from gray(lane))
#pragma unroll
    for (int r = 0; r < 16; ++r) {
      sv[r].x = __shfl(sv[r].x, permSrc);
      sv[r].y = __shfl(sv[r].y, permSrc);
    }
    // q=5: control wire5 = lane bit0, target wire6 = reg bit3 -> cond swap r<->r^8
    {
      const bool c5 = (lane & 1) != 0;
#pragma unroll
      for (int r = 0; r < 8; ++r) {
        f32x2 a = sv[r], b = sv[r + 8];
        sv[r] = c5 ? b : a;
        sv[r + 8] = c5 ? a : b;
      }
    }
    // q=6..8 composed: register gather new[j] = old[gray(j)]
    // cycles: (2 3) (4 6 5 7) (8 12 10 15) (9 13 11 14)
    {
      f32x2 t;
      t = sv[2]; sv[2] = sv[3]; sv[3] = t;
      t = sv[4]; sv[4] = sv[6]; sv[6] = sv[5]; sv[5] = sv[7]; sv[7] = t;
      t = sv[8]; sv[8] = sv[12]; sv[12] = sv[10]; sv[10] = sv[15]; sv[15] = t;
      t = sv[9]; sv[9] = sv[13]; sv[13] = sv[11]; sv[11] = sv[14]; sv[14] = t;
    }
    // q=9: control wire9 = reg bit0, target wire0 = lane bit5 -> odd r swap lane^32
#pragma unroll
    for (int r = 1; r < 16; r += 2) {
      sv[r].x = __shfl_xor(sv[r].x, 32);
      sv[r].y = __shfl_xor(sv[r].y, 32);
    }
  }

  // ---------- epilogue ----------
  float tot = 0.f, t0 = 0.f, t1 = 0.f, t2 = 0.f, t3 = 0.f;
#pragma unroll
  for (int r = 0; r < 16; ++r) {
    float pv = sv[r].x * sv[r].x + sv[r].y * sv[r].y;
    tot += pv;
    if (r & 1) t0 += pv;
    if (r & 2) t1 += pv;
    if (r & 4) t2 += pv;
    if (r & 8) t3 += pv;
  }
  // full sums of register-bit partials (result in all lanes)
  const float S3 = wave_sum_h(t3);
  const float S2 = wave_sum_h(t2);
  const float S1 = wave_sum_h(t1);
  const float S0 = wave_sum_h(t0);
  // Walsh-Hadamard across lanes: lane L holds sum_i (-1)^popcnt(L&i) tot_i.
  float v = tot, h;
  h = shfl_xor_f<1>(v);  v = (lane & 1)  ? h - v : v + h;
  h = shfl_xor_f<2>(v);  v = (lane & 2)  ? h - v : v + h;
  h = shfl_xor_f<4>(v);  v = (lane & 4)  ? h - v : v + h;
  h = shfl_xor_f<8>(v);  v = (lane & 8)  ? h - v : v + h;
  h = shfl_xor_f<16>(v); v = (lane & 16) ? h - v : v + h;
  h = shfl_xor_f<32>(v); v = (lane & 32) ? h - v : v + h;

  float* o = out + wid * NQ;
  if (lane == 32) o[0] = v;  // wire0 sign = lane bit5
  if (lane == 16) o[1] = v;
  if (lane == 8)  o[2] = v;
  if (lane == 4)  o[3] = v;
  if (lane == 2)  o[4] = v;
  if (lane == 1)  o[5] = v;  // wire5 sign = lane bit0
  if (lane == 0) {
    o[6] = v - 2.f * S3;  // wire6 = reg bit3; v(lane0) = sum(tot)
    o[7] = v - 2.f * S2;
    o[8] = v - 2.f * S1;
    o[9] = v - 2.f * S0;
  }
}

extern "C" void kernel_launch(void* const* d_in, const int* in_sizes, int n_in,
                              void* d_out, int out_size, void* d_ws, size_t ws_size,
                              hipStream_t stream) {
  const float* x = (const float*)d_in[0];
  const float* w = (const float*)d_in[1];
  float* out = (float*)d_out;
  const int batch = in_sizes[0] / NA;
  const int wavesPerBlock = 4;  // 256 threads
  const int blocks = (batch + wavesPerBlock - 1) / wavesPerBlock;
  qsim_kernel<<<blocks, 256, 0, stream>>>(x, w, out, batch);
}